// Round 4
// baseline (1511.739 us; speedup 1.0000x reference)
//
#include <hip/hip_runtime.h>
#include <cstdint>
#include <cstddef>

// Problem dims
static constexpr int Mrows = 4096;   // B*N = 8*512
static constexpr int K1 = 4608;      // D_IN
static constexpr int N1 = 4608;      // D_HID
static constexpr int N2 = 1152;      // D_OUT
static constexpr int SPLITK = 2;     // layer-2 K split

typedef float  f32x4  __attribute__((ext_vector_type(4)));
typedef __bf16 bf16x8 __attribute__((ext_vector_type(8)));

__device__ __forceinline__ unsigned short f2bf(float f) {
  unsigned int u = __float_as_uint(f);
  u += 0x7fffu + ((u >> 16) & 1u);           // RNE
  return (unsigned short)(u >> 16);
}
__device__ __forceinline__ float bf2f(unsigned short h) {
  return __uint_as_float(((unsigned int)h) << 16);
}
__device__ __forceinline__ float cleanf(float s) {
  if (__builtin_isnan(s)) return 1e-5f;
  if (__builtin_isinf(s)) return 1.0f;
  return s;
}

// ---------------------------------------------------------------------------
// prep_in: f32 -> bf16 conversion of mu_in/sigma_in + row sums of mu^2, sigma
// ---------------------------------------------------------------------------
__global__ __launch_bounds__(256) void prep_in(
    const float* __restrict__ mu, const float* __restrict__ sg,
    unsigned short* __restrict__ A1, unsigned short* __restrict__ As,
    float* __restrict__ rmu2, float* __restrict__ rsg)
{
  const int row = blockIdx.x;
  const int tid = threadIdx.x;
  const float4* mup = (const float4*)(mu + (size_t)row * K1);
  const float4* sgp = (const float4*)(sg + (size_t)row * K1);
  ushort4* a1p = (ushort4*)(A1 + (size_t)row * K1);
  ushort4* asp = (ushort4*)(As + (size_t)row * K1);
  float smu = 0.f, ssg = 0.f;
  for (int j = tid; j < K1 / 4; j += 256) {
    float4 m4 = mup[j];
    float4 s4 = sgp[j];
    smu += m4.x*m4.x + m4.y*m4.y + m4.z*m4.z + m4.w*m4.w;
    ssg += s4.x + s4.y + s4.z + s4.w;
    a1p[j] = make_ushort4(f2bf(m4.x), f2bf(m4.y), f2bf(m4.z), f2bf(m4.w));
    asp[j] = make_ushort4(f2bf(s4.x), f2bf(s4.y), f2bf(s4.z), f2bf(s4.w));
  }
  __shared__ float red[2][4];
  for (int off = 32; off; off >>= 1) {
    smu += __shfl_down(smu, off);
    ssg += __shfl_down(ssg, off);
  }
  const int lane = tid & 63, wv = tid >> 6;
  if (!lane) { red[0][wv] = smu; red[1][wv] = ssg; }
  __syncthreads();
  if (tid == 0) {
    rmu2[row] = red[0][0] + red[0][1] + red[0][2] + red[0][3];
    rsg[row]  = red[1][0] + red[1][1] + red[1][2] + red[1][3];
  }
}

// ---------------------------------------------------------------------------
// prep_w: transpose+convert w[K,N] f32 -> Bt[N,K] bf16 and Bsq[N,K]=bf16(w^2)
// + sum of w^2 (KL) via one atomic per block.
// ---------------------------------------------------------------------------
__global__ __launch_bounds__(256) void prep_w(
    const float* __restrict__ w, unsigned short* __restrict__ Bt,
    unsigned short* __restrict__ Bsq, float* __restrict__ sumsq, int sumidx,
    int K, int N)
{
  __shared__ float t[32][33];
  const int kt = blockIdx.x * 32;
  const int nt = blockIdx.y * 32;
  const int tx = threadIdx.x & 31;
  const int ty = threadIdx.x >> 5;   // 0..7
  float loc = 0.f;
#pragma unroll
  for (int i = 0; i < 32; i += 8) {
    float v = w[(size_t)(kt + ty + i) * N + (nt + tx)];
    t[ty + i][tx] = v;
    loc += v * v;
  }
  __syncthreads();
#pragma unroll
  for (int i = 0; i < 32; i += 8) {
    float v = t[tx][ty + i];                  // = w[kt+tx][nt+ty+i]
    size_t o = (size_t)(nt + ty + i) * K + (kt + tx);
    Bt[o]  = f2bf(v);
    Bsq[o] = f2bf(v * v);
  }
  __shared__ float red[4];
  for (int off = 32; off; off >>= 1) loc += __shfl_down(loc, off);
  const int lane = threadIdx.x & 63, wv = threadIdx.x >> 6;
  if (!lane) red[wv] = loc;
  __syncthreads();
  if (threadIdx.x == 0)
    atomicAdd(&sumsq[sumidx], red[0] + red[1] + red[2] + red[3]);
}

// ---------------------------------------------------------------------------
// kl_prep: softplus vectors ws1/ws2, KL scalar
// ---------------------------------------------------------------------------
__global__ __launch_bounds__(256) void kl_prep(
    const float* __restrict__ wsig1, const float* __restrict__ wsig2,
    const float* __restrict__ sumsq, float* __restrict__ ws1,
    float* __restrict__ ws2, float* __restrict__ outkl)
{
  const int tid = threadIdx.x;
  float s1 = 0.f, l1 = 0.f, s2 = 0.f, l2 = 0.f;
  for (int j = tid; j < N1; j += 256) {
    float x = wsig1[j];
    float sp = (x > 20.f) ? x : log1pf(expf(x));
    ws1[j] = sp; s1 += sp; l1 += logf(sp);
  }
  for (int j = tid; j < N2; j += 256) {
    float x = wsig2[j];
    float sp = (x > 20.f) ? x : log1pf(expf(x));
    ws2[j] = sp; s2 += sp; l2 += logf(sp);
  }
  __shared__ float red[4][4];
  for (int off = 32; off; off >>= 1) {
    s1 += __shfl_down(s1, off); l1 += __shfl_down(l1, off);
    s2 += __shfl_down(s2, off); l2 += __shfl_down(l2, off);
  }
  const int lane = tid & 63, wv = tid >> 6;
  if (!lane) { red[0][wv] = s1; red[1][wv] = l1; red[2][wv] = s2; red[3][wv] = l2; }
  __syncthreads();
  if (tid == 0) {
    float S1v = red[0][0] + red[0][1] + red[0][2] + red[0][3];
    float L1v = red[1][0] + red[1][1] + red[1][2] + red[1][3];
    float S2v = red[2][0] + red[2][1] + red[2][2] + red[2][3];
    float L2v = red[3][0] + red[3][1] + red[3][2] + red[3][3];
    const float d = 4608.f;   // w_mu.shape[0] for BOTH layers
    float kl1 = 0.5f * (d * (S1v / (float)N1) + sumsq[0] / (float)N1 - d - d * (L1v / (float)N1));
    float kl2 = 0.5f * (d * (S2v / (float)N2) + sumsq[1] / (float)N2 - d - d * (L2v / (float)N2));
    outkl[0] = kl1 + kl2;
  }
}

// ---------------------------------------------------------------------------
// gemm_bt: C[M,N] (slice z) = A[M,k-slice] * Bt[N,k-slice]^T
// 128x128 tile, 4 waves, BK=64 (32 KB LDS), 32 MFMAs + 16 ds_read_b128 per
// wave per barrier round-trip (2x the BK=32 version — K-step is latency-
// dominated, so doubling work/step amortizes the vmcnt(0)+barrier drain).
// One accumulator set (64 AGPR) keeps ~3 blocks/CU (R3's fused 128-AGPR
// variant dropped to 2 blocks/CU and was neutral).
// XOR chunk swizzle (low 2 bits) on the global-fetch side: 0 bank conflicts.
// Natural block order (R2 supertile swizzle regressed fetch 244->440 MB).
// ---------------------------------------------------------------------------
#define GLD16(gp, lp) __builtin_amdgcn_global_load_lds( \
    (__attribute__((address_space(1))) void*)(unsigned short*)(gp), \
    (__attribute__((address_space(3))) void*)(lp), 16, 0, 0)

__device__ __forceinline__ void storeC(float v, float* p) { *p = v; }
__device__ __forceinline__ void storeC(float v, unsigned short* p) { *p = f2bf(v); }

template <typename CT>
__global__ __launch_bounds__(256) void gemm_bt(
    const unsigned short* __restrict__ A, const unsigned short* __restrict__ Bt,
    CT* __restrict__ C, int M, int N, int Kstride, int Klen)
{
  __shared__ unsigned short lA[128 * 64];
  __shared__ unsigned short lB[128 * 64];
  const int tid = threadIdx.x;
  const int lane = tid & 63;
  const int wave = tid >> 6;

  const int m0 = blockIdx.y * 128;
  const int n0 = blockIdx.x * 128;
  const int wm = (wave & 1) * 64;
  const int wn = (wave >> 1) * 64;

  // split-K slice
  const int koff = blockIdx.z * Klen;
  A += koff;
  Bt += koff;
  C += (size_t)blockIdx.z * M * N;

  f32x4 acc[4][4];
#pragma unroll
  for (int i = 0; i < 4; i++)
#pragma unroll
    for (int j = 0; j < 4; j++) acc[i][j] = (f32x4){0.f, 0.f, 0.f, 0.f};

  // staging: 1024 chunks (8 bf16 each) per matrix, 4 per thread.
  // LDS slot c holds global chunk ((c&3)^((row>>1)&3)) | (c&4), row=c>>3.
  const unsigned short* gA[4];
  const unsigned short* gB[4];
  unsigned short* sA[4];
  unsigned short* sB[4];
#pragma unroll
  for (int q = 0; q < 4; q++) {
    const int c = tid + 256 * q;
    const int row = c >> 3;
    const int gkc = ((c & 3) ^ ((row >> 1) & 3)) | (c & 4);
    gA[q] = A + (size_t)(m0 + row) * Kstride + gkc * 8;
    gB[q] = Bt + (size_t)(n0 + row) * Kstride + gkc * 8;
    sA[q] = &lA[c * 8];
    sB[q] = &lB[c * 8];
  }

  // fragment read offsets (elements), h = k-half (0: k 0..31, 1: k 32..63)
  const int fm = lane & 15;
  const int kq = lane >> 4;          // 8-wide k chunk within half
  int aoff[2][4], boff[2][4];
#pragma unroll
  for (int h = 0; h < 2; h++)
#pragma unroll
    for (int i = 0; i < 4; i++) {
      int ra = wm + i * 16 + fm;
      aoff[h][i] = ra * 64 + (((kq ^ ((ra >> 1) & 3)) | (h << 2)) * 8);
      int rb = wn + i * 16 + fm;
      boff[h][i] = rb * 64 + (((kq ^ ((rb >> 1) & 3)) | (h << 2)) * 8);
    }

  const int ksteps = Klen >> 6;
  for (int kt = 0; kt < ksteps; kt++) {
    __syncthreads();                       // protect LDS from prior readers
#pragma unroll
    for (int q = 0; q < 4; q++) { GLD16(gA[q], sA[q]); GLD16(gB[q], sB[q]); }
#pragma unroll
    for (int q = 0; q < 4; q++) { gA[q] += 64; gB[q] += 64; }
    __syncthreads();                       // drain staging
#pragma unroll
    for (int h = 0; h < 2; h++) {
      bf16x8 af[4], bfr[4];
#pragma unroll
      for (int i = 0; i < 4; i++) af[i] = *(const bf16x8*)&lA[aoff[h][i]];
#pragma unroll
      for (int i = 0; i < 4; i++) bfr[i] = *(const bf16x8*)&lB[boff[h][i]];
#pragma unroll
      for (int i = 0; i < 4; i++)
#pragma unroll
        for (int j = 0; j < 4; j++)
          acc[i][j] = __builtin_amdgcn_mfma_f32_16x16x32_bf16(af[i], bfr[j], acc[i][j], 0, 0, 0);
    }
  }

  // epilogue: C/D layout col=lane&15, row=(lane>>4)*4+reg
  const int rr = (lane >> 4) * 4;
  const int cc = lane & 15;
#pragma unroll
  for (int i = 0; i < 4; i++) {
    const int grow = m0 + wm + i * 16 + rr;
#pragma unroll
    for (int j = 0; j < 4; j++) {
      const int gcol = n0 + wn + j * 16 + cc;
      CT* cp = C + (size_t)grow * N + gcol;
#pragma unroll
      for (int r = 0; r < 4; r++) storeC(acc[i][j][r], cp + (size_t)r * N);
    }
  }
}

// ---------------------------------------------------------------------------
// mid: layer-1 epilogue: sigma assembly, GELU moments, dropout, bf16 emit,
// row sums for layer-2 Sigma_2/Sigma_3 terms.
// ---------------------------------------------------------------------------
__global__ __launch_bounds__(256) void mid_kernel(
    const unsigned short* __restrict__ mu1, const unsigned short* __restrict__ S1,
    const int* __restrict__ mask1, const float* __restrict__ ws1,
    const float* __restrict__ rmu2, const float* __restrict__ rsg,
    unsigned short* __restrict__ A2, unsigned short* __restrict__ As2,
    float* __restrict__ r2mu, float* __restrict__ r2sg)
{
  const int row = blockIdx.x;
  const int tid = threadIdx.x;
  const float rterm = rmu2[row] + rsg[row];
  const ushort4* mup = (const ushort4*)(mu1 + (size_t)row * N1);
  const ushort4* s1p = (const ushort4*)(S1 + (size_t)row * N1);
  const int4* mkp = (const int4*)(mask1 + (size_t)row * N1);
  const float4* wsp = (const float4*)ws1;
  ushort4* a2p = (ushort4*)(A2 + (size_t)row * N1);
  ushort4* as2p = (ushort4*)(As2 + (size_t)row * N1);
  float smu = 0.f, ssg = 0.f;
  for (int j = tid; j < N1 / 4; j += 256) {
    ushort4 m4 = mup[j]; ushort4 s4 = s1p[j]; int4 k4 = mkp[j]; float4 w4 = wsp[j];
    float xv[4] = {bf2f(m4.x), bf2f(m4.y), bf2f(m4.z), bf2f(m4.w)};
    float Sv[4] = {bf2f(s4.x), bf2f(s4.y), bf2f(s4.z), bf2f(s4.w)};
    float wv[4] = {w4.x, w4.y, w4.z, w4.w};
    int   kv[4] = {k4.x, k4.y, k4.z, k4.w};
    unsigned short oa[4], os[4];
#pragma unroll
    for (int t = 0; t < 4; t++) {
      float sig1 = cleanf(Sv[t] + rterm * wv[t]);
      float x = xv[t];
      float cdf = 0.5f * (1.f + erff(x * 0.70710678118654752f));
      float pdf = expf(-0.5f * x * x) * 0.3989422804014327f;
      float g = cdf + x * pdf;
      float mu2v = x * cdf;
      float sig2 = g * g * sig1;
      float mm = (float)kv[t];
      float mu3 = mu2v * mm * (1.f / 0.9f);
      float sig3 = cleanf(sig2 * mm * (1.f / 4608.f));
      smu += mu3 * mu3;
      ssg += sig3;
      oa[t] = f2bf(mu3);
      os[t] = f2bf(sig3);
    }
    a2p[j] = make_ushort4(oa[0], oa[1], oa[2], oa[3]);
    as2p[j] = make_ushort4(os[0], os[1], os[2], os[3]);
  }
  __shared__ float red[2][4];
  for (int off = 32; off; off >>= 1) {
    smu += __shfl_down(smu, off);
    ssg += __shfl_down(ssg, off);
  }
  const int lane = tid & 63, wv2 = tid >> 6;
  if (!lane) { red[0][wv2] = smu; red[1][wv2] = ssg; }
  __syncthreads();
  if (tid == 0) {
    r2mu[row] = red[0][0] + red[0][1] + red[0][2] + red[0][3];
    r2sg[row] = red[1][0] + red[1][1] + red[1][2] + red[1][3];
  }
}

// ---------------------------------------------------------------------------
// final: split-K reduction + layer-2 epilogue + dropout2 + outputs
// ---------------------------------------------------------------------------
__global__ __launch_bounds__(256) void final_kernel(
    const float* __restrict__ pmu, const float* __restrict__ psig,
    const int* __restrict__ mask2, const float* __restrict__ ws2,
    const float* __restrict__ r2mu, const float* __restrict__ r2sg,
    float* __restrict__ out_mu, float* __restrict__ out_sig)
{
  const int row = blockIdx.x;
  const int tid = threadIdx.x;
  const float rterm = r2mu[row] + r2sg[row];
  const size_t sstride = (size_t)Mrows * N2;
  const float4* mup0 = (const float4*)(pmu + (size_t)row * N2);
  const float4* sbp0 = (const float4*)(psig + (size_t)row * N2);
  const int4* mkp = (const int4*)(mask2 + (size_t)row * N2);
  const float4* wsp = (const float4*)ws2;
  float4* omp = (float4*)(out_mu + (size_t)row * N2);
  float4* osp = (float4*)(out_sig + (size_t)row * N2);
  const size_t s4 = sstride / 4;
  for (int j = tid; j < N2 / 4; j += 256) {
    float4 m4 = mup0[j];
    float4 sb = sbp0[j];
#pragma unroll
    for (int s = 1; s < SPLITK; s++) {
      float4 a = mup0[j + s * s4];
      float4 b = sbp0[j + s * s4];
      m4.x += a.x; m4.y += a.y; m4.z += a.z; m4.w += a.w;
      sb.x += b.x; sb.y += b.y; sb.z += b.z; sb.w += b.w;
    }
    int4 k4 = mkp[j]; float4 w4 = wsp[j];
    float mo[4], so[4];
    float mv[4] = {m4.x, m4.y, m4.z, m4.w};
    float sv[4] = {sb.x, sb.y, sb.z, sb.w};
    float wv[4] = {w4.x, w4.y, w4.z, w4.w};
    int   kv[4] = {k4.x, k4.y, k4.z, k4.w};
#pragma unroll
    for (int t = 0; t < 4; t++) {
      float sig4 = cleanf(sv[t] + rterm * wv[t]);
      float mm = (float)kv[t];
      float mu5 = mv[t] * mm * (1.f / 0.9f);
      float sig5 = cleanf(sig4 * mm * (1.f / 1152.f));
      mo[t] = mu5;
      so[t] = cleanf(sig5);
    }
    omp[j] = make_float4(mo[0], mo[1], mo[2], mo[3]);
    osp[j] = make_float4(so[0], so[1], so[2], so[3]);
  }
}

// ---------------------------------------------------------------------------
extern "C" void kernel_launch(void* const* d_in, const int* in_sizes, int n_in,
                              void* d_out, int out_size, void* d_ws, size_t ws_size,
                              hipStream_t stream)
{
  const float* mu_in = (const float*)d_in[0];
  const float* sg_in = (const float*)d_in[1];
  const int* mask1 = (const int*)d_in[2];
  const int* mask2 = (const int*)d_in[3];
  const float* w_mu1 = (const float*)d_in[4];
  const float* wsig1 = (const float*)d_in[5];
  const float* w_mu2 = (const float*)d_in[6];
  const float* wsig2 = (const float*)d_in[7];
  float* out = (float*)d_out;

  char* ws = (char*)d_ws;
  // Fixed layout with explicit overlays (bytes):
  const size_t oA1  = 0;                           // 37,748,736  A1 / A2
  const size_t oAs  = oA1  + (size_t)37748736;     // As / As2
  const size_t oB1t = oAs  + (size_t)37748736;     // 42,467,328  B1t ; later pmu
  const size_t oB1q = oB1t + (size_t)42467328;     // B1q
  const size_t oB2t = oB1q + (size_t)42467328;     // 10,616,832
  const size_t oB2q = oB2t + (size_t)10616832;
  const size_t oMu1 = oB2q + (size_t)10616832;     // 37,748,736  mu1b ; later psig
  const size_t oS1  = oMu1 + (size_t)37748736;     // S1b16
  const size_t oVec = oS1  + (size_t)37748736;

  unsigned short* A1    = (unsigned short*)(ws + oA1);
  unsigned short* As    = (unsigned short*)(ws + oAs);
  unsigned short* B1t   = (unsigned short*)(ws + oB1t);
  unsigned short* B1q   = (unsigned short*)(ws + oB1q);
  unsigned short* B2t   = (unsigned short*)(ws + oB2t);
  unsigned short* B2q   = (unsigned short*)(ws + oB2q);
  unsigned short* mu1b  = (unsigned short*)(ws + oMu1);
  unsigned short* S1b16 = (unsigned short*)(ws + oS1);
  float* pmu  = (float*)(ws + oB1t);   // SPLITK x M x N2 f32 partials (B1t/B1q dead)
  float* psig = (float*)(ws + oMu1);   // SPLITK x M x N2 f32 partials (mu1b/S1b16 dead)

  float* rmu2 = (float*)(ws + oVec);
  float* rsg  = rmu2 + Mrows;
  float* r2mu = rsg + Mrows;
  float* r2sg = r2mu + Mrows;
  float* ws1v = r2sg + Mrows;
  float* ws2v = ws1v + N1;
  float* sumsq = ws2v + N2;

  hipMemsetAsync(sumsq, 0, 2 * sizeof(float), stream);

  prep_in<<<Mrows, 256, 0, stream>>>(mu_in, sg_in, A1, As, rmu2, rsg);
  prep_w<<<dim3(K1 / 32, N1 / 32), 256, 0, stream>>>(w_mu1, B1t, B1q, sumsq, 0, K1, N1);
  prep_w<<<dim3(K1 / 32, N2 / 32), 256, 0, stream>>>(w_mu2, B2t, B2q, sumsq, 1, K1, N2);
  kl_prep<<<1, 256, 0, stream>>>(wsig1, wsig2, sumsq, ws1v, ws2v, out + (size_t)2 * Mrows * N2);

  // layer 1: full-K GEMMs, bf16 out, BK=64
  gemm_bt<unsigned short><<<dim3(N1 / 128, Mrows / 128, 1), 256, 0, stream>>>(
      A1, B1t, mu1b, Mrows, N1, K1, K1);
  gemm_bt<unsigned short><<<dim3(N1 / 128, Mrows / 128, 1), 256, 0, stream>>>(
      As, B1q, S1b16, Mrows, N1, K1, K1);

  mid_kernel<<<Mrows, 256, 0, stream>>>(mu1b, S1b16, mask1, ws1v, rmu2, rsg, A1, As, r2mu, r2sg);

  // layer 2: split-K=2 GEMMs into f32 partials, BK=64
  gemm_bt<float><<<dim3(N2 / 128, Mrows / 128, SPLITK), 256, 0, stream>>>(
      A1, B2t, pmu, Mrows, N2, K1, K1 / SPLITK);
  gemm_bt<float><<<dim3(N2 / 128, Mrows / 128, SPLITK), 256, 0, stream>>>(
      As, B2q, psig, Mrows, N2, K1, K1 / SPLITK);

  final_kernel<<<Mrows, 256, 0, stream>>>(pmu, psig, mask2, ws2v, r2mu, r2sg,
                                          out, out + (size_t)Mrows * N2);
  (void)in_sizes; (void)n_in; (void)out_size; (void)ws_size;
}

// Round 5
// 1143.789 us; speedup vs baseline: 1.3217x; 1.3217x over previous
//
#include <hip/hip_runtime.h>
#include <cstdint>
#include <cstddef>

// Problem dims
static constexpr int Mrows = 4096;   // B*N = 8*512
static constexpr int K1 = 4608;      // D_IN
static constexpr int N1 = 4608;      // D_HID
static constexpr int N2 = 1152;      // D_OUT
static constexpr int SPLITK = 2;     // layer-2 K split
static constexpr int NPART1 = (K1 / 32) * (N1 / 32);   // 20736 prep_w partials (w1)
static constexpr int NPART2 = (K1 / 32) * (N2 / 32);   // 5184 partials (w2)

typedef float  f32x4  __attribute__((ext_vector_type(4)));
typedef __bf16 bf16x8 __attribute__((ext_vector_type(8)));

__device__ __forceinline__ unsigned short f2bf(float f) {
  unsigned int u = __float_as_uint(f);
  u += 0x7fffu + ((u >> 16) & 1u);           // RNE
  return (unsigned short)(u >> 16);
}
__device__ __forceinline__ float bf2f(unsigned short h) {
  return __uint_as_float(((unsigned int)h) << 16);
}
__device__ __forceinline__ float cleanf(float s) {
  if (__builtin_isnan(s)) return 1e-5f;
  if (__builtin_isinf(s)) return 1.0f;
  return s;
}

// ---------------------------------------------------------------------------
// prep_in: f32 -> bf16 conversion of mu_in/sigma_in + row sums of mu^2, sigma
// ---------------------------------------------------------------------------
__global__ __launch_bounds__(256) void prep_in(
    const float* __restrict__ mu, const float* __restrict__ sg,
    unsigned short* __restrict__ A1, unsigned short* __restrict__ As,
    float* __restrict__ rmu2, float* __restrict__ rsg)
{
  const int row = blockIdx.x;
  const int tid = threadIdx.x;
  const float4* mup = (const float4*)(mu + (size_t)row * K1);
  const float4* sgp = (const float4*)(sg + (size_t)row * K1);
  ushort4* a1p = (ushort4*)(A1 + (size_t)row * K1);
  ushort4* asp = (ushort4*)(As + (size_t)row * K1);
  float smu = 0.f, ssg = 0.f;
  for (int j = tid; j < K1 / 4; j += 256) {
    float4 m4 = mup[j];
    float4 s4 = sgp[j];
    smu += m4.x*m4.x + m4.y*m4.y + m4.z*m4.z + m4.w*m4.w;
    ssg += s4.x + s4.y + s4.z + s4.w;
    a1p[j] = make_ushort4(f2bf(m4.x), f2bf(m4.y), f2bf(m4.z), f2bf(m4.w));
    asp[j] = make_ushort4(f2bf(s4.x), f2bf(s4.y), f2bf(s4.z), f2bf(s4.w));
  }
  __shared__ float red[2][4];
  for (int off = 32; off; off >>= 1) {
    smu += __shfl_down(smu, off);
    ssg += __shfl_down(ssg, off);
  }
  const int lane = tid & 63, wv = tid >> 6;
  if (!lane) { red[0][wv] = smu; red[1][wv] = ssg; }
  __syncthreads();
  if (tid == 0) {
    rmu2[row] = red[0][0] + red[0][1] + red[0][2] + red[0][3];
    rsg[row]  = red[1][0] + red[1][1] + red[1][2] + red[1][3];
  }
}

// ---------------------------------------------------------------------------
// prep_w: transpose+convert w[K,N] f32 -> Bt[N,K] bf16 and Bsq[N,K]=bf16(w^2)
// Sum of w^2 written as ONE PARTIAL PER BLOCK (no atomics — R4 analysis:
// 20736 same-address device atomics were serializing ~hundreds of µs).
// ---------------------------------------------------------------------------
__global__ __launch_bounds__(256) void prep_w(
    const float* __restrict__ w, unsigned short* __restrict__ Bt,
    unsigned short* __restrict__ Bsq, float* __restrict__ partials,
    int K, int N)
{
  __shared__ float t[32][33];
  const int kt = blockIdx.x * 32;
  const int nt = blockIdx.y * 32;
  const int tx = threadIdx.x & 31;
  const int ty = threadIdx.x >> 5;   // 0..7
  float loc = 0.f;
#pragma unroll
  for (int i = 0; i < 32; i += 8) {
    float v = w[(size_t)(kt + ty + i) * N + (nt + tx)];
    t[ty + i][tx] = v;
    loc += v * v;
  }
  __syncthreads();
#pragma unroll
  for (int i = 0; i < 32; i += 8) {
    float v = t[tx][ty + i];                  // = w[kt+tx][nt+ty+i]
    size_t o = (size_t)(nt + ty + i) * K + (kt + tx);
    Bt[o]  = f2bf(v);
    Bsq[o] = f2bf(v * v);
  }
  __shared__ float red[4];
  for (int off = 32; off; off >>= 1) loc += __shfl_down(loc, off);
  const int lane = threadIdx.x & 63, wv = threadIdx.x >> 6;
  if (!lane) red[wv] = loc;
  __syncthreads();
  if (threadIdx.x == 0)
    partials[blockIdx.y * gridDim.x + blockIdx.x] = red[0] + red[1] + red[2] + red[3];
}

// ---------------------------------------------------------------------------
// kl_prep: softplus vectors ws1/ws2, reduce prep_w partials, KL scalar
// ---------------------------------------------------------------------------
__global__ __launch_bounds__(256) void kl_prep(
    const float* __restrict__ wsig1, const float* __restrict__ wsig2,
    const float* __restrict__ part1, const float* __restrict__ part2,
    float* __restrict__ ws1, float* __restrict__ ws2, float* __restrict__ outkl)
{
  const int tid = threadIdx.x;
  float s1 = 0.f, l1 = 0.f, s2 = 0.f, l2 = 0.f, q1 = 0.f, q2 = 0.f;
  for (int j = tid; j < N1; j += 256) {
    float x = wsig1[j];
    float sp = (x > 20.f) ? x : log1pf(expf(x));
    ws1[j] = sp; s1 += sp; l1 += logf(sp);
  }
  for (int j = tid; j < N2; j += 256) {
    float x = wsig2[j];
    float sp = (x > 20.f) ? x : log1pf(expf(x));
    ws2[j] = sp; s2 += sp; l2 += logf(sp);
  }
  for (int j = tid; j < NPART1; j += 256) q1 += part1[j];
  for (int j = tid; j < NPART2; j += 256) q2 += part2[j];
  __shared__ float red[6][4];
  for (int off = 32; off; off >>= 1) {
    s1 += __shfl_down(s1, off); l1 += __shfl_down(l1, off);
    s2 += __shfl_down(s2, off); l2 += __shfl_down(l2, off);
    q1 += __shfl_down(q1, off); q2 += __shfl_down(q2, off);
  }
  const int lane = tid & 63, wv = tid >> 6;
  if (!lane) {
    red[0][wv] = s1; red[1][wv] = l1; red[2][wv] = s2;
    red[3][wv] = l2; red[4][wv] = q1; red[5][wv] = q2;
  }
  __syncthreads();
  if (tid == 0) {
    float S1v = red[0][0] + red[0][1] + red[0][2] + red[0][3];
    float L1v = red[1][0] + red[1][1] + red[1][2] + red[1][3];
    float S2v = red[2][0] + red[2][1] + red[2][2] + red[2][3];
    float L2v = red[3][0] + red[3][1] + red[3][2] + red[3][3];
    float Q1v = red[4][0] + red[4][1] + red[4][2] + red[4][3];
    float Q2v = red[5][0] + red[5][1] + red[5][2] + red[5][3];
    const float d = 4608.f;   // w_mu.shape[0] for BOTH layers
    float kl1 = 0.5f * (d * (S1v / (float)N1) + Q1v / (float)N1 - d - d * (L1v / (float)N1));
    float kl2 = 0.5f * (d * (S2v / (float)N2) + Q2v / (float)N2 - d - d * (L2v / (float)N2));
    outkl[0] = kl1 + kl2;
  }
}

// ---------------------------------------------------------------------------
// gemm_bt: C[M,N] (slice z) = A[M,k-slice] * Bt[N,k-slice]^T
// R1-exact structure (best known: 277 µs, 628 TF, 0 bank conflicts):
// 128x128 tile, 4 waves, BK=32 (16 KB LDS), 16x16x32 MFMA, width-16
// global_load_lds, XOR chunk swizzle on the global-fetch side.
// BK=64 (R4) regressed: 128 B row stride killed the odd-row bank offset ->
// 4-way conflicts (2.1e7) + occupancy drop. Supertile swizzle (R2) and
// mu+sigma fusion (R3) also regressed. Do not reintroduce without new evidence.
// ---------------------------------------------------------------------------
#define GLD16(gp, lp) __builtin_amdgcn_global_load_lds( \
    (__attribute__((address_space(1))) void*)(unsigned short*)(gp), \
    (__attribute__((address_space(3))) void*)(lp), 16, 0, 0)

__device__ __forceinline__ void storeC(float v, float* p) { *p = v; }
__device__ __forceinline__ void storeC(float v, unsigned short* p) { *p = f2bf(v); }

template <typename CT>
__global__ __launch_bounds__(256) void gemm_bt(
    const unsigned short* __restrict__ A, const unsigned short* __restrict__ Bt,
    CT* __restrict__ C, int M, int N, int Kstride, int Klen)
{
  __shared__ unsigned short lA[128 * 32];
  __shared__ unsigned short lB[128 * 32];
  const int tid = threadIdx.x;
  const int lane = tid & 63;
  const int wave = tid >> 6;

  const int m0 = blockIdx.y * 128;
  const int n0 = blockIdx.x * 128;
  const int wm = (wave & 1) * 64;
  const int wn = (wave >> 1) * 64;

  // split-K slice
  const int koff = blockIdx.z * Klen;
  A += koff;
  Bt += koff;
  C += (size_t)blockIdx.z * M * N;

  f32x4 acc[4][4];
#pragma unroll
  for (int i = 0; i < 4; i++)
#pragma unroll
    for (int j = 0; j < 4; j++) acc[i][j] = (f32x4){0.f, 0.f, 0.f, 0.f};

  // staging: chunk c -> LDS slot c (linear, forced); global chunk = (c&3) ^ swz(row)
  const int c0 = tid, c1 = tid + 256;
  const int r0s = c0 >> 2, k0s = (c0 & 3) ^ ((r0s >> 1) & 3);
  const int r1s = c1 >> 2, k1s = (c1 & 3) ^ ((r1s >> 1) & 3);
  const unsigned short* gA0 = A + (size_t)(m0 + r0s) * Kstride + k0s * 8;
  const unsigned short* gA1 = A + (size_t)(m0 + r1s) * Kstride + k1s * 8;
  const unsigned short* gB0 = Bt + (size_t)(n0 + r0s) * Kstride + k0s * 8;
  const unsigned short* gB1 = Bt + (size_t)(n0 + r1s) * Kstride + k1s * 8;
  unsigned short* lA0 = &lA[c0 * 8];
  unsigned short* lA1 = &lA[c1 * 8];
  unsigned short* lB0 = &lB[c0 * 8];
  unsigned short* lB1 = &lB[c1 * 8];

  // fragment read offsets (elements) — match the store-side swizzle
  const int fm = lane & 15;
  const int kq = lane >> 4;          // which 8-wide k chunk
  int aoff[4], boff[4];
#pragma unroll
  for (int i = 0; i < 4; i++) {
    int ra = wm + i * 16 + fm;
    aoff[i] = ra * 32 + ((kq ^ ((ra >> 1) & 3)) * 8);
    int rb = wn + i * 16 + fm;
    boff[i] = rb * 32 + ((kq ^ ((rb >> 1) & 3)) * 8);
  }

  const int ksteps = Klen >> 5;
  for (int kt = 0; kt < ksteps; kt++) {
    __syncthreads();                       // protect LDS from prior readers
    GLD16(gA0, lA0); GLD16(gA1, lA1);
    GLD16(gB0, lB0); GLD16(gB1, lB1);
    gA0 += 32; gA1 += 32; gB0 += 32; gB1 += 32;
    __syncthreads();                       // drain staging
    bf16x8 af[4], bfr[4];
#pragma unroll
    for (int i = 0; i < 4; i++) af[i] = *(const bf16x8*)&lA[aoff[i]];
#pragma unroll
    for (int i = 0; i < 4; i++) bfr[i] = *(const bf16x8*)&lB[boff[i]];
#pragma unroll
    for (int i = 0; i < 4; i++)
#pragma unroll
      for (int j = 0; j < 4; j++)
        acc[i][j] = __builtin_amdgcn_mfma_f32_16x16x32_bf16(af[i], bfr[j], acc[i][j], 0, 0, 0);
  }

  // epilogue: C/D layout col=lane&15, row=(lane>>4)*4+reg
  const int rr = (lane >> 4) * 4;
  const int cc = lane & 15;
#pragma unroll
  for (int i = 0; i < 4; i++) {
    const int grow = m0 + wm + i * 16 + rr;
#pragma unroll
    for (int j = 0; j < 4; j++) {
      const int gcol = n0 + wn + j * 16 + cc;
      CT* cp = C + (size_t)grow * N + gcol;
#pragma unroll
      for (int r = 0; r < 4; r++) storeC(acc[i][j][r], cp + (size_t)r * N);
    }
  }
}

// ---------------------------------------------------------------------------
// mid: layer-1 epilogue: sigma assembly, GELU moments, dropout, bf16 emit,
// row sums for layer-2 Sigma_2/Sigma_3 terms.
// ---------------------------------------------------------------------------
__global__ __launch_bounds__(256) void mid_kernel(
    const unsigned short* __restrict__ mu1, const unsigned short* __restrict__ S1,
    const int* __restrict__ mask1, const float* __restrict__ ws1,
    const float* __restrict__ rmu2, const float* __restrict__ rsg,
    unsigned short* __restrict__ A2, unsigned short* __restrict__ As2,
    float* __restrict__ r2mu, float* __restrict__ r2sg)
{
  const int row = blockIdx.x;
  const int tid = threadIdx.x;
  const float rterm = rmu2[row] + rsg[row];
  const ushort4* mup = (const ushort4*)(mu1 + (size_t)row * N1);
  const ushort4* s1p = (const ushort4*)(S1 + (size_t)row * N1);
  const int4* mkp = (const int4*)(mask1 + (size_t)row * N1);
  const float4* wsp = (const float4*)ws1;
  ushort4* a2p = (ushort4*)(A2 + (size_t)row * N1);
  ushort4* as2p = (ushort4*)(As2 + (size_t)row * N1);
  float smu = 0.f, ssg = 0.f;
  for (int j = tid; j < N1 / 4; j += 256) {
    ushort4 m4 = mup[j]; ushort4 s4 = s1p[j]; int4 k4 = mkp[j]; float4 w4 = wsp[j];
    float xv[4] = {bf2f(m4.x), bf2f(m4.y), bf2f(m4.z), bf2f(m4.w)};
    float Sv[4] = {bf2f(s4.x), bf2f(s4.y), bf2f(s4.z), bf2f(s4.w)};
    float wv[4] = {w4.x, w4.y, w4.z, w4.w};
    int   kv[4] = {k4.x, k4.y, k4.z, k4.w};
    unsigned short oa[4], os[4];
#pragma unroll
    for (int t = 0; t < 4; t++) {
      float sig1 = cleanf(Sv[t] + rterm * wv[t]);
      float x = xv[t];
      float cdf = 0.5f * (1.f + erff(x * 0.70710678118654752f));
      float pdf = expf(-0.5f * x * x) * 0.3989422804014327f;
      float g = cdf + x * pdf;
      float mu2v = x * cdf;
      float sig2 = g * g * sig1;
      float mm = (float)kv[t];
      float mu3 = mu2v * mm * (1.f / 0.9f);
      float sig3 = cleanf(sig2 * mm * (1.f / 4608.f));
      smu += mu3 * mu3;
      ssg += sig3;
      oa[t] = f2bf(mu3);
      os[t] = f2bf(sig3);
    }
    a2p[j] = make_ushort4(oa[0], oa[1], oa[2], oa[3]);
    as2p[j] = make_ushort4(os[0], os[1], os[2], os[3]);
  }
  __shared__ float red[2][4];
  for (int off = 32; off; off >>= 1) {
    smu += __shfl_down(smu, off);
    ssg += __shfl_down(ssg, off);
  }
  const int lane = tid & 63, wv2 = tid >> 6;
  if (!lane) { red[0][wv2] = smu; red[1][wv2] = ssg; }
  __syncthreads();
  if (tid == 0) {
    r2mu[row] = red[0][0] + red[0][1] + red[0][2] + red[0][3];
    r2sg[row] = red[1][0] + red[1][1] + red[1][2] + red[1][3];
  }
}

// ---------------------------------------------------------------------------
// final: split-K reduction + layer-2 epilogue + dropout2 + outputs
// ---------------------------------------------------------------------------
__global__ __launch_bounds__(256) void final_kernel(
    const float* __restrict__ pmu, const float* __restrict__ psig,
    const int* __restrict__ mask2, const float* __restrict__ ws2,
    const float* __restrict__ r2mu, const float* __restrict__ r2sg,
    float* __restrict__ out_mu, float* __restrict__ out_sig)
{
  const int row = blockIdx.x;
  const int tid = threadIdx.x;
  const float rterm = r2mu[row] + r2sg[row];
  const size_t sstride = (size_t)Mrows * N2;
  const float4* mup0 = (const float4*)(pmu + (size_t)row * N2);
  const float4* sbp0 = (const float4*)(psig + (size_t)row * N2);
  const int4* mkp = (const int4*)(mask2 + (size_t)row * N2);
  const float4* wsp = (const float4*)ws2;
  float4* omp = (float4*)(out_mu + (size_t)row * N2);
  float4* osp = (float4*)(out_sig + (size_t)row * N2);
  const size_t s4 = sstride / 4;
  for (int j = tid; j < N2 / 4; j += 256) {
    float4 m4 = mup0[j];
    float4 sb = sbp0[j];
#pragma unroll
    for (int s = 1; s < SPLITK; s++) {
      float4 a = mup0[j + s * s4];
      float4 b = sbp0[j + s * s4];
      m4.x += a.x; m4.y += a.y; m4.z += a.z; m4.w += a.w;
      sb.x += b.x; sb.y += b.y; sb.z += b.z; sb.w += b.w;
    }
    int4 k4 = mkp[j]; float4 w4 = wsp[j];
    float mo[4], so[4];
    float mv[4] = {m4.x, m4.y, m4.z, m4.w};
    float sv[4] = {sb.x, sb.y, sb.z, sb.w};
    float wv[4] = {w4.x, w4.y, w4.z, w4.w};
    int   kv[4] = {k4.x, k4.y, k4.z, k4.w};
#pragma unroll
    for (int t = 0; t < 4; t++) {
      float sig4 = cleanf(sv[t] + rterm * wv[t]);
      float mm = (float)kv[t];
      float mu5 = mv[t] * mm * (1.f / 0.9f);
      float sig5 = cleanf(sig4 * mm * (1.f / 1152.f));
      mo[t] = mu5;
      so[t] = cleanf(sig5);
    }
    omp[j] = make_float4(mo[0], mo[1], mo[2], mo[3]);
    osp[j] = make_float4(so[0], so[1], so[2], so[3]);
  }
}

// ---------------------------------------------------------------------------
extern "C" void kernel_launch(void* const* d_in, const int* in_sizes, int n_in,
                              void* d_out, int out_size, void* d_ws, size_t ws_size,
                              hipStream_t stream)
{
  const float* mu_in = (const float*)d_in[0];
  const float* sg_in = (const float*)d_in[1];
  const int* mask1 = (const int*)d_in[2];
  const int* mask2 = (const int*)d_in[3];
  const float* w_mu1 = (const float*)d_in[4];
  const float* wsig1 = (const float*)d_in[5];
  const float* w_mu2 = (const float*)d_in[6];
  const float* wsig2 = (const float*)d_in[7];
  float* out = (float*)d_out;

  char* ws = (char*)d_ws;
  // Fixed layout with explicit overlays (bytes):
  const size_t oA1  = 0;                           // 37,748,736  A1 / A2
  const size_t oAs  = oA1  + (size_t)37748736;     // As / As2
  const size_t oB1t = oAs  + (size_t)37748736;     // 42,467,328  B1t ; later pmu
  const size_t oB1q = oB1t + (size_t)42467328;     // B1q
  const size_t oB2t = oB1q + (size_t)42467328;     // 10,616,832
  const size_t oB2q = oB2t + (size_t)10616832;
  const size_t oMu1 = oB2q + (size_t)10616832;     // 37,748,736  mu1b ; later psig
  const size_t oS1  = oMu1 + (size_t)37748736;     // S1b16
  const size_t oVec = oS1  + (size_t)37748736;

  unsigned short* A1    = (unsigned short*)(ws + oA1);
  unsigned short* As    = (unsigned short*)(ws + oAs);
  unsigned short* B1t   = (unsigned short*)(ws + oB1t);
  unsigned short* B1q   = (unsigned short*)(ws + oB1q);
  unsigned short* B2t   = (unsigned short*)(ws + oB2t);
  unsigned short* B2q   = (unsigned short*)(ws + oB2q);
  unsigned short* mu1b  = (unsigned short*)(ws + oMu1);
  unsigned short* S1b16 = (unsigned short*)(ws + oS1);
  float* pmu  = (float*)(ws + oB1t);   // SPLITK x M x N2 f32 partials (B1t/B1q dead)
  float* psig = (float*)(ws + oMu1);   // SPLITK x M x N2 f32 partials (mu1b/S1b16 dead)

  float* rmu2 = (float*)(ws + oVec);
  float* rsg  = rmu2 + Mrows;
  float* r2mu = rsg + Mrows;
  float* r2sg = r2mu + Mrows;
  float* ws1v = r2sg + Mrows;
  float* ws2v = ws1v + N1;
  float* part1 = ws2v + N2;            // NPART1 floats
  float* part2 = part1 + NPART1;       // NPART2 floats

  prep_in<<<Mrows, 256, 0, stream>>>(mu_in, sg_in, A1, As, rmu2, rsg);
  prep_w<<<dim3(K1 / 32, N1 / 32), 256, 0, stream>>>(w_mu1, B1t, B1q, part1, K1, N1);
  prep_w<<<dim3(K1 / 32, N2 / 32), 256, 0, stream>>>(w_mu2, B2t, B2q, part2, K1, N2);
  kl_prep<<<1, 256, 0, stream>>>(wsig1, wsig2, part1, part2, ws1v, ws2v,
                                 out + (size_t)2 * Mrows * N2);

  // layer 1: full-K GEMMs, bf16 out, BK=32 (R1-exact best-known)
  gemm_bt<unsigned short><<<dim3(N1 / 128, Mrows / 128, 1), 256, 0, stream>>>(
      A1, B1t, mu1b, Mrows, N1, K1, K1);
  gemm_bt<unsigned short><<<dim3(N1 / 128, Mrows / 128, 1), 256, 0, stream>>>(
      As, B1q, S1b16, Mrows, N1, K1, K1);

  mid_kernel<<<Mrows, 256, 0, stream>>>(mu1b, S1b16, mask1, ws1v, rmu2, rsg, A1, As, r2mu, r2sg);

  // layer 2: split-K=2 GEMMs into f32 partials
  gemm_bt<float><<<dim3(N2 / 128, Mrows / 128, SPLITK), 256, 0, stream>>>(
      A1, B2t, pmu, Mrows, N2, K1, K1 / SPLITK);
  gemm_bt<float><<<dim3(N2 / 128, Mrows / 128, SPLITK), 256, 0, stream>>>(
      As, B2q, psig, Mrows, N2, K1, K1 / SPLITK);

  final_kernel<<<Mrows, 256, 0, stream>>>(pmu, psig, mask2, ws2v, r2mu, r2sg,
                                          out, out + (size_t)Mrows * N2);
  (void)in_sizes; (void)n_in; (void)out_size; (void)ws_size;
}

// Round 6
// 1011.793 us; speedup vs baseline: 1.4941x; 1.1305x over previous
//
#include <hip/hip_runtime.h>
#include <cstdint>
#include <cstddef>

// Problem dims
static constexpr int Mrows = 4096;   // B*N = 8*512
static constexpr int K1 = 4608;      // D_IN
static constexpr int N1 = 4608;      // D_HID
static constexpr int N2 = 1152;      // D_OUT
static constexpr int SPLITK = 2;     // layer-2 K split
static constexpr int NPART1 = (K1 / 32) * (N1 / 32);   // 20736 prep_w partials (w1)
static constexpr int NPART2 = (K1 / 32) * (N2 / 32);   // 5184 partials (w2)

typedef float  f32x4  __attribute__((ext_vector_type(4)));
typedef __bf16 bf16x8 __attribute__((ext_vector_type(8)));

__device__ __forceinline__ unsigned short f2bf(float f) {
  unsigned int u = __float_as_uint(f);
  u += 0x7fffu + ((u >> 16) & 1u);           // RNE
  return (unsigned short)(u >> 16);
}
__device__ __forceinline__ float bf2f(unsigned short h) {
  return __uint_as_float(((unsigned int)h) << 16);
}
__device__ __forceinline__ float cleanf(float s) {
  if (__builtin_isnan(s)) return 1e-5f;
  if (__builtin_isinf(s)) return 1.0f;
  return s;
}

// ---------------------------------------------------------------------------
// prep_in: f32 -> bf16 conversion of mu_in/sigma_in + row sums of mu^2, sigma
// ---------------------------------------------------------------------------
__global__ __launch_bounds__(256) void prep_in(
    const float* __restrict__ mu, const float* __restrict__ sg,
    unsigned short* __restrict__ A1, unsigned short* __restrict__ As,
    float* __restrict__ rmu2, float* __restrict__ rsg)
{
  const int row = blockIdx.x;
  const int tid = threadIdx.x;
  const float4* mup = (const float4*)(mu + (size_t)row * K1);
  const float4* sgp = (const float4*)(sg + (size_t)row * K1);
  ushort4* a1p = (ushort4*)(A1 + (size_t)row * K1);
  ushort4* asp = (ushort4*)(As + (size_t)row * K1);
  float smu = 0.f, ssg = 0.f;
  for (int j = tid; j < K1 / 4; j += 256) {
    float4 m4 = mup[j];
    float4 s4 = sgp[j];
    smu += m4.x*m4.x + m4.y*m4.y + m4.z*m4.z + m4.w*m4.w;
    ssg += s4.x + s4.y + s4.z + s4.w;
    a1p[j] = make_ushort4(f2bf(m4.x), f2bf(m4.y), f2bf(m4.z), f2bf(m4.w));
    asp[j] = make_ushort4(f2bf(s4.x), f2bf(s4.y), f2bf(s4.z), f2bf(s4.w));
  }
  __shared__ float red[2][4];
  for (int off = 32; off; off >>= 1) {
    smu += __shfl_down(smu, off);
    ssg += __shfl_down(ssg, off);
  }
  const int lane = tid & 63, wv = tid >> 6;
  if (!lane) { red[0][wv] = smu; red[1][wv] = ssg; }
  __syncthreads();
  if (tid == 0) {
    rmu2[row] = red[0][0] + red[0][1] + red[0][2] + red[0][3];
    rsg[row]  = red[1][0] + red[1][1] + red[1][2] + red[1][3];
  }
}

// ---------------------------------------------------------------------------
// prep_w: transpose+convert w[K,N] f32 -> Bt[N,K] bf16 and Bsq[N,K]=bf16(w^2)
// Sum of w^2 written as one partial per block (no atomics — R4/R5: the
// same-address atomic storm cost ~290 µs).
// ---------------------------------------------------------------------------
__global__ __launch_bounds__(256) void prep_w(
    const float* __restrict__ w, unsigned short* __restrict__ Bt,
    unsigned short* __restrict__ Bsq, float* __restrict__ partials,
    int K, int N)
{
  __shared__ float t[32][33];
  const int kt = blockIdx.x * 32;
  const int nt = blockIdx.y * 32;
  const int tx = threadIdx.x & 31;
  const int ty = threadIdx.x >> 5;   // 0..7
  float loc = 0.f;
#pragma unroll
  for (int i = 0; i < 32; i += 8) {
    float v = w[(size_t)(kt + ty + i) * N + (nt + tx)];
    t[ty + i][tx] = v;
    loc += v * v;
  }
  __syncthreads();
#pragma unroll
  for (int i = 0; i < 32; i += 8) {
    float v = t[tx][ty + i];                  // = w[kt+tx][nt+ty+i]
    size_t o = (size_t)(nt + ty + i) * K + (kt + tx);
    Bt[o]  = f2bf(v);
    Bsq[o] = f2bf(v * v);
  }
  __shared__ float red[4];
  for (int off = 32; off; off >>= 1) loc += __shfl_down(loc, off);
  const int lane = threadIdx.x & 63, wv = threadIdx.x >> 6;
  if (!lane) red[wv] = loc;
  __syncthreads();
  if (threadIdx.x == 0)
    partials[blockIdx.y * gridDim.x + blockIdx.x] = red[0] + red[1] + red[2] + red[3];
}

// ---------------------------------------------------------------------------
// kl_prep: softplus vectors ws1/ws2, reduce prep_w partials, KL scalar
// ---------------------------------------------------------------------------
__global__ __launch_bounds__(256) void kl_prep(
    const float* __restrict__ wsig1, const float* __restrict__ wsig2,
    const float* __restrict__ part1, const float* __restrict__ part2,
    float* __restrict__ ws1, float* __restrict__ ws2, float* __restrict__ outkl)
{
  const int tid = threadIdx.x;
  float s1 = 0.f, l1 = 0.f, s2 = 0.f, l2 = 0.f, q1 = 0.f, q2 = 0.f;
  for (int j = tid; j < N1; j += 256) {
    float x = wsig1[j];
    float sp = (x > 20.f) ? x : log1pf(expf(x));
    ws1[j] = sp; s1 += sp; l1 += logf(sp);
  }
  for (int j = tid; j < N2; j += 256) {
    float x = wsig2[j];
    float sp = (x > 20.f) ? x : log1pf(expf(x));
    ws2[j] = sp; s2 += sp; l2 += logf(sp);
  }
  for (int j = tid; j < NPART1; j += 256) q1 += part1[j];
  for (int j = tid; j < NPART2; j += 256) q2 += part2[j];
  __shared__ float red[6][4];
  for (int off = 32; off; off >>= 1) {
    s1 += __shfl_down(s1, off); l1 += __shfl_down(l1, off);
    s2 += __shfl_down(s2, off); l2 += __shfl_down(l2, off);
    q1 += __shfl_down(q1, off); q2 += __shfl_down(q2, off);
  }
  const int lane = tid & 63, wv = tid >> 6;
  if (!lane) {
    red[0][wv] = s1; red[1][wv] = l1; red[2][wv] = s2;
    red[3][wv] = l2; red[4][wv] = q1; red[5][wv] = q2;
  }
  __syncthreads();
  if (tid == 0) {
    float S1v = red[0][0] + red[0][1] + red[0][2] + red[0][3];
    float L1v = red[1][0] + red[1][1] + red[1][2] + red[1][3];
    float S2v = red[2][0] + red[2][1] + red[2][2] + red[2][3];
    float L2v = red[3][0] + red[3][1] + red[3][2] + red[3][3];
    float Q1v = red[4][0] + red[4][1] + red[4][2] + red[4][3];
    float Q2v = red[5][0] + red[5][1] + red[5][2] + red[5][3];
    const float d = 4608.f;   // w_mu.shape[0] for BOTH layers
    float kl1 = 0.5f * (d * (S1v / (float)N1) + Q1v / (float)N1 - d - d * (L1v / (float)N1));
    float kl2 = 0.5f * (d * (S2v / (float)N2) + Q2v / (float)N2 - d - d * (L2v / (float)N2));
    outkl[0] = kl1 + kl2;
  }
}

// ---------------------------------------------------------------------------
// gemm_bt2: z-packed dual GEMM. blockIdx.z: bit0 selects (mu | sigma)
// operand/output set; bits>=1 select the split-K slice. Packing both
// products into one dispatch fills whole occupancy rounds (R5 analysis:
// separate 1152-block dispatches ran 1.5 rounds each, second half-empty).
// Per-block: R1-proven 128x128 tile, 4 waves, BK=32, 16x16x32 MFMA,
// width-16 global_load_lds, XOR chunk swizzle (0 conflicts).
// NEW: double-buffered LDS, ONE barrier per K-step, prefetch issued before
// the MFMA block — staging (vmcnt) overlaps ds_read/MFMA (lgkmcnt).
// ---------------------------------------------------------------------------
#define GLD16(gp, lp) __builtin_amdgcn_global_load_lds( \
    (__attribute__((address_space(1))) void*)(unsigned short*)(gp), \
    (__attribute__((address_space(3))) void*)(lp), 16, 0, 0)

__device__ __forceinline__ void storeC(float v, float* p) { *p = v; }
__device__ __forceinline__ void storeC(float v, unsigned short* p) { *p = f2bf(v); }

template <typename CT>
__global__ __launch_bounds__(256) void gemm_bt2(
    const unsigned short* __restrict__ Aa, const unsigned short* __restrict__ Ab,
    const unsigned short* __restrict__ Ba, const unsigned short* __restrict__ Bb,
    CT* __restrict__ Ca, CT* __restrict__ Cb,
    int M, int N, int Kstride, int Klen)
{
  __shared__ unsigned short lA[2][128 * 32];
  __shared__ unsigned short lB[2][128 * 32];
  const int tid = threadIdx.x;
  const int lane = tid & 63;
  const int wave = tid >> 6;

  const int which = blockIdx.z & 1;
  const int slice = blockIdx.z >> 1;
  const unsigned short* A  = which ? Ab : Aa;
  const unsigned short* Bt = which ? Bb : Ba;
  CT* C = which ? Cb : Ca;

  const int m0 = blockIdx.y * 128;
  const int n0 = blockIdx.x * 128;
  const int wm = (wave & 1) * 64;
  const int wn = (wave >> 1) * 64;

  // split-K slice
  A += slice * Klen;
  Bt += slice * Klen;
  C += (size_t)slice * M * N;

  f32x4 acc[4][4];
#pragma unroll
  for (int i = 0; i < 4; i++)
#pragma unroll
    for (int j = 0; j < 4; j++) acc[i][j] = (f32x4){0.f, 0.f, 0.f, 0.f};

  // staging: chunk c -> LDS slot c (linear, forced); global chunk = (c&3) ^ swz(row)
  const int c0 = tid, c1 = tid + 256;
  const int r0s = c0 >> 2, k0s = (c0 & 3) ^ ((r0s >> 1) & 3);
  const int r1s = c1 >> 2, k1s = (c1 & 3) ^ ((r1s >> 1) & 3);
  const unsigned short* gA0 = A + (size_t)(m0 + r0s) * Kstride + k0s * 8;
  const unsigned short* gA1 = A + (size_t)(m0 + r1s) * Kstride + k1s * 8;
  const unsigned short* gB0 = Bt + (size_t)(n0 + r0s) * Kstride + k0s * 8;
  const unsigned short* gB1 = Bt + (size_t)(n0 + r1s) * Kstride + k1s * 8;

  // fragment read offsets (elements) — match the store-side swizzle
  const int fm = lane & 15;
  const int kq = lane >> 4;          // which 8-wide k chunk
  int aoff[4], boff[4];
#pragma unroll
  for (int i = 0; i < 4; i++) {
    int ra = wm + i * 16 + fm;
    aoff[i] = ra * 32 + ((kq ^ ((ra >> 1) & 3)) * 8);
    int rb = wn + i * 16 + fm;
    boff[i] = rb * 32 + ((kq ^ ((rb >> 1) & 3)) * 8);
  }

  // prefetch tile 0 into buffer 0
  GLD16(gA0, &lA[0][c0 * 8]); GLD16(gA1, &lA[0][c1 * 8]);
  GLD16(gB0, &lB[0][c0 * 8]); GLD16(gB1, &lB[0][c1 * 8]);
  gA0 += 32; gA1 += 32; gB0 += 32; gB1 += 32;

  const int ksteps = Klen >> 5;
  int cur = 0;
  for (int kt = 0; kt < ksteps; kt++) {
    // one barrier per step: drains buf[cur] staging (vmcnt0) and makes all
    // lanes' ds_reads of buf[cur^1] complete -> safe to overwrite it below.
    __syncthreads();
    if (kt + 1 < ksteps) {
      const int nb = cur ^ 1;
      GLD16(gA0, &lA[nb][c0 * 8]); GLD16(gA1, &lA[nb][c1 * 8]);
      GLD16(gB0, &lB[nb][c0 * 8]); GLD16(gB1, &lB[nb][c1 * 8]);
      gA0 += 32; gA1 += 32; gB0 += 32; gB1 += 32;
    }
    bf16x8 af[4], bfr[4];
#pragma unroll
    for (int i = 0; i < 4; i++) af[i] = *(const bf16x8*)&lA[cur][aoff[i]];
#pragma unroll
    for (int i = 0; i < 4; i++) bfr[i] = *(const bf16x8*)&lB[cur][boff[i]];
#pragma unroll
    for (int i = 0; i < 4; i++)
#pragma unroll
      for (int j = 0; j < 4; j++)
        acc[i][j] = __builtin_amdgcn_mfma_f32_16x16x32_bf16(af[i], bfr[j], acc[i][j], 0, 0, 0);
    cur ^= 1;
  }

  // epilogue: C/D layout col=lane&15, row=(lane>>4)*4+reg
  const int rr = (lane >> 4) * 4;
  const int cc = lane & 15;
#pragma unroll
  for (int i = 0; i < 4; i++) {
    const int grow = m0 + wm + i * 16 + rr;
#pragma unroll
    for (int j = 0; j < 4; j++) {
      const int gcol = n0 + wn + j * 16 + cc;
      CT* cp = C + (size_t)grow * N + gcol;
#pragma unroll
      for (int r = 0; r < 4; r++) storeC(acc[i][j][r], cp + (size_t)r * N);
    }
  }
}

// ---------------------------------------------------------------------------
// mid: layer-1 epilogue: sigma assembly, GELU moments, dropout, bf16 emit,
// row sums for layer-2 Sigma_2/Sigma_3 terms.
// ---------------------------------------------------------------------------
__global__ __launch_bounds__(256) void mid_kernel(
    const unsigned short* __restrict__ mu1, const unsigned short* __restrict__ S1,
    const int* __restrict__ mask1, const float* __restrict__ ws1,
    const float* __restrict__ rmu2, const float* __restrict__ rsg,
    unsigned short* __restrict__ A2, unsigned short* __restrict__ As2,
    float* __restrict__ r2mu, float* __restrict__ r2sg)
{
  const int row = blockIdx.x;
  const int tid = threadIdx.x;
  const float rterm = rmu2[row] + rsg[row];
  const ushort4* mup = (const ushort4*)(mu1 + (size_t)row * N1);
  const ushort4* s1p = (const ushort4*)(S1 + (size_t)row * N1);
  const int4* mkp = (const int4*)(mask1 + (size_t)row * N1);
  const float4* wsp = (const float4*)ws1;
  ushort4* a2p = (ushort4*)(A2 + (size_t)row * N1);
  ushort4* as2p = (ushort4*)(As2 + (size_t)row * N1);
  float smu = 0.f, ssg = 0.f;
  for (int j = tid; j < N1 / 4; j += 256) {
    ushort4 m4 = mup[j]; ushort4 s4 = s1p[j]; int4 k4 = mkp[j]; float4 w4 = wsp[j];
    float xv[4] = {bf2f(m4.x), bf2f(m4.y), bf2f(m4.z), bf2f(m4.w)};
    float Sv[4] = {bf2f(s4.x), bf2f(s4.y), bf2f(s4.z), bf2f(s4.w)};
    float wv[4] = {w4.x, w4.y, w4.z, w4.w};
    int   kv[4] = {k4.x, k4.y, k4.z, k4.w};
    unsigned short oa[4], os[4];
#pragma unroll
    for (int t = 0; t < 4; t++) {
      float sig1 = cleanf(Sv[t] + rterm * wv[t]);
      float x = xv[t];
      float cdf = 0.5f * (1.f + erff(x * 0.70710678118654752f));
      float pdf = expf(-0.5f * x * x) * 0.3989422804014327f;
      float g = cdf + x * pdf;
      float mu2v = x * cdf;
      float sig2 = g * g * sig1;
      float mm = (float)kv[t];
      float mu3 = mu2v * mm * (1.f / 0.9f);
      float sig3 = cleanf(sig2 * mm * (1.f / 4608.f));
      smu += mu3 * mu3;
      ssg += sig3;
      oa[t] = f2bf(mu3);
      os[t] = f2bf(sig3);
    }
    a2p[j] = make_ushort4(oa[0], oa[1], oa[2], oa[3]);
    as2p[j] = make_ushort4(os[0], os[1], os[2], os[3]);
  }
  __shared__ float red[2][4];
  for (int off = 32; off; off >>= 1) {
    smu += __shfl_down(smu, off);
    ssg += __shfl_down(ssg, off);
  }
  const int lane = tid & 63, wv2 = tid >> 6;
  if (!lane) { red[0][wv2] = smu; red[1][wv2] = ssg; }
  __syncthreads();
  if (tid == 0) {
    r2mu[row] = red[0][0] + red[0][1] + red[0][2] + red[0][3];
    r2sg[row] = red[1][0] + red[1][1] + red[1][2] + red[1][3];
  }
}

// ---------------------------------------------------------------------------
// final: split-K reduction + layer-2 epilogue + dropout2 + outputs
// ---------------------------------------------------------------------------
__global__ __launch_bounds__(256) void final_kernel(
    const float* __restrict__ pmu, const float* __restrict__ psig,
    const int* __restrict__ mask2, const float* __restrict__ ws2,
    const float* __restrict__ r2mu, const float* __restrict__ r2sg,
    float* __restrict__ out_mu, float* __restrict__ out_sig)
{
  const int row = blockIdx.x;
  const int tid = threadIdx.x;
  const float rterm = r2mu[row] + r2sg[row];
  const size_t sstride = (size_t)Mrows * N2;
  const float4* mup0 = (const float4*)(pmu + (size_t)row * N2);
  const float4* sbp0 = (const float4*)(psig + (size_t)row * N2);
  const int4* mkp = (const int4*)(mask2 + (size_t)row * N2);
  const float4* wsp = (const float4*)ws2;
  float4* omp = (float4*)(out_mu + (size_t)row * N2);
  float4* osp = (float4*)(out_sig + (size_t)row * N2);
  const size_t s4 = sstride / 4;
  for (int j = tid; j < N2 / 4; j += 256) {
    float4 m4 = mup0[j];
    float4 sb = sbp0[j];
#pragma unroll
    for (int s = 1; s < SPLITK; s++) {
      float4 a = mup0[j + s * s4];
      float4 b = sbp0[j + s * s4];
      m4.x += a.x; m4.y += a.y; m4.z += a.z; m4.w += a.w;
      sb.x += b.x; sb.y += b.y; sb.z += b.z; sb.w += b.w;
    }
    int4 k4 = mkp[j]; float4 w4 = wsp[j];
    float mo[4], so[4];
    float mv[4] = {m4.x, m4.y, m4.z, m4.w};
    float sv[4] = {sb.x, sb.y, sb.z, sb.w};
    float wv[4] = {w4.x, w4.y, w4.z, w4.w};
    int   kv[4] = {k4.x, k4.y, k4.z, k4.w};
#pragma unroll
    for (int t = 0; t < 4; t++) {
      float sig4 = cleanf(sv[t] + rterm * wv[t]);
      float mm = (float)kv[t];
      float mu5 = mv[t] * mm * (1.f / 0.9f);
      float sig5 = cleanf(sig4 * mm * (1.f / 1152.f));
      mo[t] = mu5;
      so[t] = cleanf(sig5);
    }
    omp[j] = make_float4(mo[0], mo[1], mo[2], mo[3]);
    osp[j] = make_float4(so[0], so[1], so[2], so[3]);
  }
}

// ---------------------------------------------------------------------------
extern "C" void kernel_launch(void* const* d_in, const int* in_sizes, int n_in,
                              void* d_out, int out_size, void* d_ws, size_t ws_size,
                              hipStream_t stream)
{
  const float* mu_in = (const float*)d_in[0];
  const float* sg_in = (const float*)d_in[1];
  const int* mask1 = (const int*)d_in[2];
  const int* mask2 = (const int*)d_in[3];
  const float* w_mu1 = (const float*)d_in[4];
  const float* wsig1 = (const float*)d_in[5];
  const float* w_mu2 = (const float*)d_in[6];
  const float* wsig2 = (const float*)d_in[7];
  float* out = (float*)d_out;

  char* ws = (char*)d_ws;
  // Fixed layout with explicit overlays (bytes):
  const size_t oA1  = 0;                           // 37,748,736  A1 / A2
  const size_t oAs  = oA1  + (size_t)37748736;     // As / As2
  const size_t oB1t = oAs  + (size_t)37748736;     // 42,467,328  B1t ; later pmu
  const size_t oB1q = oB1t + (size_t)42467328;     // B1q
  const size_t oB2t = oB1q + (size_t)42467328;     // 10,616,832
  const size_t oB2q = oB2t + (size_t)10616832;
  const size_t oMu1 = oB2q + (size_t)10616832;     // 37,748,736  mu1b ; later psig
  const size_t oS1  = oMu1 + (size_t)37748736;     // S1b16
  const size_t oVec = oS1  + (size_t)37748736;

  unsigned short* A1    = (unsigned short*)(ws + oA1);
  unsigned short* As    = (unsigned short*)(ws + oAs);
  unsigned short* B1t   = (unsigned short*)(ws + oB1t);
  unsigned short* B1q   = (unsigned short*)(ws + oB1q);
  unsigned short* B2t   = (unsigned short*)(ws + oB2t);
  unsigned short* B2q   = (unsigned short*)(ws + oB2q);
  unsigned short* mu1b  = (unsigned short*)(ws + oMu1);
  unsigned short* S1b16 = (unsigned short*)(ws + oS1);
  float* pmu  = (float*)(ws + oB1t);   // SPLITK x M x N2 f32 partials (B1t/B1q dead)
  float* psig = (float*)(ws + oMu1);   // SPLITK x M x N2 f32 partials (mu1b/S1b16 dead)

  float* rmu2 = (float*)(ws + oVec);
  float* rsg  = rmu2 + Mrows;
  float* r2mu = rsg + Mrows;
  float* r2sg = r2mu + Mrows;
  float* ws1v = r2sg + Mrows;
  float* ws2v = ws1v + N1;
  float* part1 = ws2v + N2;            // NPART1 floats
  float* part2 = part1 + NPART1;       // NPART2 floats

  prep_in<<<Mrows, 256, 0, stream>>>(mu_in, sg_in, A1, As, rmu2, rsg);
  prep_w<<<dim3(K1 / 32, N1 / 32), 256, 0, stream>>>(w_mu1, B1t, B1q, part1, K1, N1);
  prep_w<<<dim3(K1 / 32, N2 / 32), 256, 0, stream>>>(w_mu2, B2t, B2q, part2, K1, N2);
  kl_prep<<<1, 256, 0, stream>>>(wsig1, wsig2, part1, part2, ws1v, ws2v,
                                 out + (size_t)2 * Mrows * N2);

  // layer 1: mu+sigma products z-packed into ONE dispatch (2304 blocks = 3
  // full rounds at 3 blocks/CU; two 1152-block dispatches each wasted half
  // a round in tail drain)
  gemm_bt2<unsigned short><<<dim3(N1 / 128, Mrows / 128, 2), 256, 0, stream>>>(
      A1, As, B1t, B1q, mu1b, S1b16, Mrows, N1, K1, K1);

  mid_kernel<<<Mrows, 256, 0, stream>>>(mu1b, S1b16, mask1, ws1v, rmu2, rsg, A1, As, r2mu, r2sg);

  // layer 2: both products x split-K=2 z-packed into one 1152-block dispatch
  gemm_bt2<float><<<dim3(N2 / 128, Mrows / 128, 2 * SPLITK), 256, 0, stream>>>(
      A1, As, B2t, B2q, pmu, psig, Mrows, N2, K1, K1 / SPLITK);

  final_kernel<<<Mrows, 256, 0, stream>>>(pmu, psig, mask2, ws2v, r2mu, r2sg,
                                          out, out + (size_t)Mrows * N2);
  (void)in_sizes; (void)n_in; (void)out_size; (void)ws_size;
}

// Round 7
// 962.376 us; speedup vs baseline: 1.5708x; 1.0513x over previous
//
#include <hip/hip_runtime.h>
#include <cstdint>
#include <cstddef>

// Problem dims
static constexpr int Mrows = 4096;   // B*N = 8*512
static constexpr int K1 = 4608;      // D_IN
static constexpr int N1 = 4608;      // D_HID
static constexpr int N2 = 1152;      // D_OUT
static constexpr int SPLITK = 2;     // layer-2 K split
static constexpr int NPART1 = (K1 / 32) * (N1 / 32);   // 20736 prep_w partials (w1)
static constexpr int NPART2 = (K1 / 32) * (N2 / 32);   // 5184 partials (w2)

// fp8 static scales (sigma stream is all-positive -> no cancellation; rel err
// of sums ~3%/sqrt(K) ~= 0.05% << 2% threshold)
static constexpr float SC_SIGIN = 256.f;     // sigma_in in [0,1] -> <=256 (<448)
static constexpr float SC_WSQ   = 4096.f;    // w^2 <= ~0.08 -> <=333 (<448)
static constexpr float SC_SIG3  = 16384.f;   // sig3 <= ~0.022 -> <=360 (<448)
static constexpr float DSC_L1   = 1.f / (SC_SIGIN * SC_WSQ);
static constexpr float DSC_L2   = 1.f / (SC_SIG3 * SC_WSQ);

typedef float  f32x4  __attribute__((ext_vector_type(4)));
typedef __bf16 bf16x8 __attribute__((ext_vector_type(8)));

__device__ __forceinline__ unsigned short f2bf(float f) {
  unsigned int u = __float_as_uint(f);
  u += 0x7fffu + ((u >> 16) & 1u);           // RNE
  return (unsigned short)(u >> 16);
}
__device__ __forceinline__ float bf2f(unsigned short h) {
  return __uint_as_float(((unsigned int)h) << 16);
}
__device__ __forceinline__ float cleanf(float s) {
  if (__builtin_isnan(s)) return 1e-5f;
  if (__builtin_isinf(s)) return 1.0f;
  return s;
}
// pack 4 floats -> 4 fp8 e4m3 (OCP, HW cvt saturates)
__device__ __forceinline__ unsigned int pk_fp8x4(float a, float b, float c, float d) {
  int p = __builtin_amdgcn_cvt_pk_fp8_f32(a, b, 0, false);
  p = __builtin_amdgcn_cvt_pk_fp8_f32(c, d, p, true);
  return (unsigned int)p;
}

// ---------------------------------------------------------------------------
// prep_in: mu -> bf16 A1; sigma -> fp8 As (x256); row sums of mu^2, sigma
// ---------------------------------------------------------------------------
__global__ __launch_bounds__(256) void prep_in(
    const float* __restrict__ mu, const float* __restrict__ sg,
    unsigned short* __restrict__ A1, unsigned char* __restrict__ As,
    float* __restrict__ rmu2, float* __restrict__ rsg)
{
  const int row = blockIdx.x;
  const int tid = threadIdx.x;
  const float4* mup = (const float4*)(mu + (size_t)row * K1);
  const float4* sgp = (const float4*)(sg + (size_t)row * K1);
  ushort4* a1p = (ushort4*)(A1 + (size_t)row * K1);
  unsigned int* asp = (unsigned int*)(As + (size_t)row * K1);
  float smu = 0.f, ssg = 0.f;
  for (int j = tid; j < K1 / 4; j += 256) {
    float4 m4 = mup[j];
    float4 s4 = sgp[j];
    smu += m4.x*m4.x + m4.y*m4.y + m4.z*m4.z + m4.w*m4.w;
    ssg += s4.x + s4.y + s4.z + s4.w;
    a1p[j] = make_ushort4(f2bf(m4.x), f2bf(m4.y), f2bf(m4.z), f2bf(m4.w));
    asp[j] = pk_fp8x4(s4.x * SC_SIGIN, s4.y * SC_SIGIN, s4.z * SC_SIGIN, s4.w * SC_SIGIN);
  }
  __shared__ float red[2][4];
  for (int off = 32; off; off >>= 1) {
    smu += __shfl_down(smu, off);
    ssg += __shfl_down(ssg, off);
  }
  const int lane = tid & 63, wv = tid >> 6;
  if (!lane) { red[0][wv] = smu; red[1][wv] = ssg; }
  __syncthreads();
  if (tid == 0) {
    rmu2[row] = red[0][0] + red[0][1] + red[0][2] + red[0][3];
    rsg[row]  = red[1][0] + red[1][1] + red[1][2] + red[1][3];
  }
}

// ---------------------------------------------------------------------------
// prep_w: transpose w[K,N] -> Bt[N,K] bf16 and Bsq[N,K] fp8(w^2 * SC_WSQ).
// One f32 partial per block for the KL sum (no atomics — R5: atomic storm
// cost ~290 µs).
// ---------------------------------------------------------------------------
__global__ __launch_bounds__(256) void prep_w(
    const float* __restrict__ w, unsigned short* __restrict__ Bt,
    unsigned char* __restrict__ Bsq, float* __restrict__ partials,
    int K, int N)
{
  __shared__ float t[32][33];
  const int kt = blockIdx.x * 32;
  const int nt = blockIdx.y * 32;
  const int tx = threadIdx.x & 31;
  const int ty = threadIdx.x >> 5;   // 0..7
  float loc = 0.f;
#pragma unroll
  for (int i = 0; i < 32; i += 8) {
    float v = w[(size_t)(kt + ty + i) * N + (nt + tx)];
    t[ty + i][tx] = v;
    loc += v * v;
  }
  __syncthreads();
#pragma unroll
  for (int i = 0; i < 32; i += 8) {
    float v = t[tx][ty + i];                  // = w[kt+tx][nt+ty+i]
    size_t o = (size_t)(nt + ty + i) * K + (kt + tx);
    Bt[o]  = f2bf(v);
    Bsq[o] = (unsigned char)(__builtin_amdgcn_cvt_pk_fp8_f32(v * v * SC_WSQ, 0.f, 0, false) & 0xff);
  }
  __shared__ float red[4];
  for (int off = 32; off; off >>= 1) loc += __shfl_down(loc, off);
  const int lane = threadIdx.x & 63, wv = threadIdx.x >> 6;
  if (!lane) red[wv] = loc;
  __syncthreads();
  if (threadIdx.x == 0)
    partials[blockIdx.y * gridDim.x + blockIdx.x] = red[0] + red[1] + red[2] + red[3];
}

// ---------------------------------------------------------------------------
// kl_prep: softplus vectors ws1/ws2, reduce prep_w partials, KL scalar
// ---------------------------------------------------------------------------
__global__ __launch_bounds__(256) void kl_prep(
    const float* __restrict__ wsig1, const float* __restrict__ wsig2,
    const float* __restrict__ part1, const float* __restrict__ part2,
    float* __restrict__ ws1, float* __restrict__ ws2, float* __restrict__ outkl)
{
  const int tid = threadIdx.x;
  float s1 = 0.f, l1 = 0.f, s2 = 0.f, l2 = 0.f, q1 = 0.f, q2 = 0.f;
  for (int j = tid; j < N1; j += 256) {
    float x = wsig1[j];
    float sp = (x > 20.f) ? x : log1pf(expf(x));
    ws1[j] = sp; s1 += sp; l1 += logf(sp);
  }
  for (int j = tid; j < N2; j += 256) {
    float x = wsig2[j];
    float sp = (x > 20.f) ? x : log1pf(expf(x));
    ws2[j] = sp; s2 += sp; l2 += logf(sp);
  }
  for (int j = tid; j < NPART1; j += 256) q1 += part1[j];
  for (int j = tid; j < NPART2; j += 256) q2 += part2[j];
  __shared__ float red[6][4];
  for (int off = 32; off; off >>= 1) {
    s1 += __shfl_down(s1, off); l1 += __shfl_down(l1, off);
    s2 += __shfl_down(s2, off); l2 += __shfl_down(l2, off);
    q1 += __shfl_down(q1, off); q2 += __shfl_down(q2, off);
  }
  const int lane = tid & 63, wv = tid >> 6;
  if (!lane) {
    red[0][wv] = s1; red[1][wv] = l1; red[2][wv] = s2;
    red[3][wv] = l2; red[4][wv] = q1; red[5][wv] = q2;
  }
  __syncthreads();
  if (tid == 0) {
    float S1v = red[0][0] + red[0][1] + red[0][2] + red[0][3];
    float L1v = red[1][0] + red[1][1] + red[1][2] + red[1][3];
    float S2v = red[2][0] + red[2][1] + red[2][2] + red[2][3];
    float L2v = red[3][0] + red[3][1] + red[3][2] + red[3][3];
    float Q1v = red[4][0] + red[4][1] + red[4][2] + red[4][3];
    float Q2v = red[5][0] + red[5][1] + red[5][2] + red[5][3];
    const float d = 4608.f;   // w_mu.shape[0] for BOTH layers
    float kl1 = 0.5f * (d * (S1v / (float)N1) + Q1v / (float)N1 - d - d * (L1v / (float)N1));
    float kl2 = 0.5f * (d * (S2v / (float)N2) + Q2v / (float)N2 - d - d * (L2v / (float)N2));
    outkl[0] = kl1 + kl2;
  }
}

// ---------------------------------------------------------------------------
// gemm_bt2: z-packed dual GEMM, heterogeneous dtype per z-bit0:
//   which=0: mu product, bf16, BK=32 (R6-proven path)
//   which=1: sigma product, fp8 e4m3, BK=64 (half LDS bytes per K — the
//            K-loop is LDS-BW-bound: 176 KB/CU/iter ≈ 92% of iter @85 B/cy)
// bits>=1 of z select the split-K slice. Double-buffered LDS, one barrier
// per K-step, prefetch before MFMA. 32 KB LDS both paths.
// ---------------------------------------------------------------------------
#define GLD16(gp, lp) __builtin_amdgcn_global_load_lds( \
    (__attribute__((address_space(1))) void*)(unsigned short*)(gp), \
    (__attribute__((address_space(3))) void*)(lp), 16, 0, 0)

__device__ __forceinline__ void storeC(float v, float* p) { *p = v; }
__device__ __forceinline__ void storeC(float v, unsigned short* p) { *p = f2bf(v); }

template <typename CT>
__global__ __launch_bounds__(256) void gemm_bt2(
    const unsigned short* __restrict__ Aa, const unsigned char* __restrict__ As8,
    const unsigned short* __restrict__ Ba, const unsigned char* __restrict__ Bq8,
    CT* __restrict__ Ca, CT* __restrict__ Cs,
    int M, int N, int Kstride, int Klen, float sdescale)
{
  __shared__ __align__(16) char smem[32768];
  const int tid = threadIdx.x;
  const int lane = tid & 63;
  const int wave = tid >> 6;

  const int which = blockIdx.z & 1;
  const int slice = blockIdx.z >> 1;

  const int m0 = blockIdx.y * 128;
  const int n0 = blockIdx.x * 128;
  const int wm = (wave & 1) * 64;
  const int wn = (wave >> 1) * 64;

  const int fm = lane & 15;
  const int kq = lane >> 4;          // 8-wide k sub-chunk

  f32x4 acc[4][4];
#pragma unroll
  for (int i = 0; i < 4; i++)
#pragma unroll
    for (int j = 0; j < 4; j++) acc[i][j] = (f32x4){0.f, 0.f, 0.f, 0.f};

  if (which == 0) {
    // ---------------- bf16 mu path (BK=32) ----------------
    const unsigned short* A  = Aa + (size_t)slice * Klen;
    const unsigned short* Bt = Ba + (size_t)slice * Klen;
    unsigned short* lA = (unsigned short*)smem;            // [2][4096]
    unsigned short* lB = (unsigned short*)(smem + 16384);  // [2][4096]

    const int c0 = tid, c1 = tid + 256;
    const int r0s = c0 >> 2, k0s = (c0 & 3) ^ ((r0s >> 1) & 3);
    const int r1s = c1 >> 2, k1s = (c1 & 3) ^ ((r1s >> 1) & 3);
    const unsigned short* gA0 = A + (size_t)(m0 + r0s) * Kstride + k0s * 8;
    const unsigned short* gA1 = A + (size_t)(m0 + r1s) * Kstride + k1s * 8;
    const unsigned short* gB0 = Bt + (size_t)(n0 + r0s) * Kstride + k0s * 8;
    const unsigned short* gB1 = Bt + (size_t)(n0 + r1s) * Kstride + k1s * 8;

    int aoff[4], boff[4];
#pragma unroll
    for (int i = 0; i < 4; i++) {
      int ra = wm + i * 16 + fm;
      aoff[i] = ra * 32 + ((kq ^ ((ra >> 1) & 3)) * 8);
      int rb = wn + i * 16 + fm;
      boff[i] = rb * 32 + ((kq ^ ((rb >> 1) & 3)) * 8);
    }

    GLD16(gA0, &lA[c0 * 8]); GLD16(gA1, &lA[c1 * 8]);
    GLD16(gB0, &lB[c0 * 8]); GLD16(gB1, &lB[c1 * 8]);
    gA0 += 32; gA1 += 32; gB0 += 32; gB1 += 32;

    const int ksteps = Klen >> 5;
    int cur = 0;
    for (int kt = 0; kt < ksteps; kt++) {
      __syncthreads();
      if (kt + 1 < ksteps) {
        const int nb = cur ^ 1;
        GLD16(gA0, &lA[nb * 4096 + c0 * 8]); GLD16(gA1, &lA[nb * 4096 + c1 * 8]);
        GLD16(gB0, &lB[nb * 4096 + c0 * 8]); GLD16(gB1, &lB[nb * 4096 + c1 * 8]);
        gA0 += 32; gA1 += 32; gB0 += 32; gB1 += 32;
      }
      bf16x8 af[4], bfr[4];
#pragma unroll
      for (int i = 0; i < 4; i++) af[i] = *(const bf16x8*)&lA[cur * 4096 + aoff[i]];
#pragma unroll
      for (int i = 0; i < 4; i++) bfr[i] = *(const bf16x8*)&lB[cur * 4096 + boff[i]];
#pragma unroll
      for (int i = 0; i < 4; i++)
#pragma unroll
        for (int j = 0; j < 4; j++)
          acc[i][j] = __builtin_amdgcn_mfma_f32_16x16x32_bf16(af[i], bfr[j], acc[i][j], 0, 0, 0);
      cur ^= 1;
    }

    CT* C = Ca + (size_t)slice * M * N;
    const int rr = (lane >> 4) * 4;
    const int cc = lane & 15;
#pragma unroll
    for (int i = 0; i < 4; i++) {
      const int grow = m0 + wm + i * 16 + rr;
#pragma unroll
      for (int j = 0; j < 4; j++) {
        const int gcol = n0 + wn + j * 16 + cc;
        CT* cp = C + (size_t)grow * N + gcol;
#pragma unroll
        for (int r = 0; r < 4; r++) storeC(acc[i][j][r], cp + (size_t)r * N);
      }
    }
  } else {
    // ---------------- fp8 sigma path (BK=64) ----------------
    // LDS granule = 16B = A[row][k16*16 .. +15]; slot s = k16*128+row, addr = s*16.
    // Frag b64 reads: ~2 lanes/bank pairs (free) — wave64 x 8B = 512B = HW min.
    const unsigned char* A  = As8 + (size_t)slice * Klen;
    const unsigned char* Bt = Bq8 + (size_t)slice * Klen;
    char* lA = smem;            // [2][8192]
    char* lB = smem + 16384;    // [2][8192]

    const int s1 = tid, s2 = tid + 256;
    const int r1 = s1 & 127, h1 = s1 >> 7;
    const int r2 = s2 & 127, h2 = s2 >> 7;
    const unsigned char* gA0 = A + (size_t)(m0 + r1) * Kstride + h1 * 16;
    const unsigned char* gA1 = A + (size_t)(m0 + r2) * Kstride + h2 * 16;
    const unsigned char* gB0 = Bt + (size_t)(n0 + r1) * Kstride + h1 * 16;
    const unsigned char* gB1 = Bt + (size_t)(n0 + r2) * Kstride + h2 * 16;

    // frag offsets: chunk c = hh*4+kq (8 fp8), addr = (c>>1)*2048 + row*16 + (c&1)*8
    int aoff8[2][4], boff8[2][4];
#pragma unroll
    for (int hh = 0; hh < 2; hh++)
#pragma unroll
      for (int i = 0; i < 4; i++) {
        const int c = hh * 4 + kq;
        aoff8[hh][i] = (c >> 1) * 2048 + (wm + i * 16 + fm) * 16 + (c & 1) * 8;
        boff8[hh][i] = (c >> 1) * 2048 + (wn + i * 16 + fm) * 16 + (c & 1) * 8;
      }

    GLD16(gA0, lA + s1 * 16); GLD16(gA1, lA + s2 * 16);
    GLD16(gB0, lB + s1 * 16); GLD16(gB1, lB + s2 * 16);
    gA0 += 64; gA1 += 64; gB0 += 64; gB1 += 64;

    const int ksteps = Klen >> 6;
    int cur = 0;
    for (int kt = 0; kt < ksteps; kt++) {
      __syncthreads();
      if (kt + 1 < ksteps) {
        const int nb = cur ^ 1;
        GLD16(gA0, lA + nb * 8192 + s1 * 16); GLD16(gA1, lA + nb * 8192 + s2 * 16);
        GLD16(gB0, lB + nb * 8192 + s1 * 16); GLD16(gB1, lB + nb * 8192 + s2 * 16);
        gA0 += 64; gA1 += 64; gB0 += 64; gB1 += 64;
      }
#pragma unroll
      for (int hh = 0; hh < 2; hh++) {
        long av[4], bv[4];
#pragma unroll
        for (int i = 0; i < 4; i++) av[i] = *(const long*)(lA + cur * 8192 + aoff8[hh][i]);
#pragma unroll
        for (int i = 0; i < 4; i++) bv[i] = *(const long*)(lB + cur * 8192 + boff8[hh][i]);
#pragma unroll
        for (int i = 0; i < 4; i++)
#pragma unroll
          for (int j = 0; j < 4; j++)
            acc[i][j] = __builtin_amdgcn_mfma_f32_16x16x32_fp8_fp8(av[i], bv[j], acc[i][j], 0, 0, 0);
      }
      cur ^= 1;
    }

    CT* C = Cs + (size_t)slice * M * N;
    const int rr = (lane >> 4) * 4;
    const int cc = lane & 15;
#pragma unroll
    for (int i = 0; i < 4; i++) {
      const int grow = m0 + wm + i * 16 + rr;
#pragma unroll
      for (int j = 0; j < 4; j++) {
        const int gcol = n0 + wn + j * 16 + cc;
        CT* cp = C + (size_t)grow * N + gcol;
#pragma unroll
        for (int r = 0; r < 4; r++) storeC(acc[i][j][r] * sdescale, cp + (size_t)r * N);
      }
    }
  }
}

// ---------------------------------------------------------------------------
// mid: layer-1 epilogue: sigma assembly, GELU moments, dropout;
// emits A2 bf16 + As2 fp8 (x SC_SIG3); row sums for layer-2 Sigma terms.
// ---------------------------------------------------------------------------
__global__ __launch_bounds__(256) void mid_kernel(
    const unsigned short* __restrict__ mu1, const unsigned short* __restrict__ S1,
    const int* __restrict__ mask1, const float* __restrict__ ws1,
    const float* __restrict__ rmu2, const float* __restrict__ rsg,
    unsigned short* __restrict__ A2, unsigned char* __restrict__ As2,
    float* __restrict__ r2mu, float* __restrict__ r2sg)
{
  const int row = blockIdx.x;
  const int tid = threadIdx.x;
  const float rterm = rmu2[row] + rsg[row];
  const ushort4* mup = (const ushort4*)(mu1 + (size_t)row * N1);
  const ushort4* s1p = (const ushort4*)(S1 + (size_t)row * N1);
  const int4* mkp = (const int4*)(mask1 + (size_t)row * N1);
  const float4* wsp = (const float4*)ws1;
  ushort4* a2p = (ushort4*)(A2 + (size_t)row * N1);
  unsigned int* as2p = (unsigned int*)(As2 + (size_t)row * N1);
  float smu = 0.f, ssg = 0.f;
  for (int j = tid; j < N1 / 4; j += 256) {
    ushort4 m4 = mup[j]; ushort4 s4 = s1p[j]; int4 k4 = mkp[j]; float4 w4 = wsp[j];
    float xv[4] = {bf2f(m4.x), bf2f(m4.y), bf2f(m4.z), bf2f(m4.w)};
    float Sv[4] = {bf2f(s4.x), bf2f(s4.y), bf2f(s4.z), bf2f(s4.w)};
    float wv[4] = {w4.x, w4.y, w4.z, w4.w};
    int   kv[4] = {k4.x, k4.y, k4.z, k4.w};
    unsigned short oa[4];
    float os[4];
#pragma unroll
    for (int t = 0; t < 4; t++) {
      float sig1 = cleanf(Sv[t] + rterm * wv[t]);
      float x = xv[t];
      float cdf = 0.5f * (1.f + erff(x * 0.70710678118654752f));
      float pdf = expf(-0.5f * x * x) * 0.3989422804014327f;
      float g = cdf + x * pdf;
      float mu2v = x * cdf;
      float sig2 = g * g * sig1;
      float mm = (float)kv[t];
      float mu3 = mu2v * mm * (1.f / 0.9f);
      float sig3 = cleanf(sig2 * mm * (1.f / 4608.f));
      smu += mu3 * mu3;
      ssg += sig3;
      oa[t] = f2bf(mu3);
      os[t] = sig3 * SC_SIG3;
    }
    a2p[j] = make_ushort4(oa[0], oa[1], oa[2], oa[3]);
    as2p[j] = pk_fp8x4(os[0], os[1], os[2], os[3]);
  }
  __shared__ float red[2][4];
  for (int off = 32; off; off >>= 1) {
    smu += __shfl_down(smu, off);
    ssg += __shfl_down(ssg, off);
  }
  const int lane = tid & 63, wv2 = tid >> 6;
  if (!lane) { red[0][wv2] = smu; red[1][wv2] = ssg; }
  __syncthreads();
  if (tid == 0) {
    r2mu[row] = red[0][0] + red[0][1] + red[0][2] + red[0][3];
    r2sg[row] = red[1][0] + red[1][1] + red[1][2] + red[1][3];
  }
}

// ---------------------------------------------------------------------------
// final: split-K reduction + layer-2 epilogue + dropout2 + outputs
// ---------------------------------------------------------------------------
__global__ __launch_bounds__(256) void final_kernel(
    const float* __restrict__ pmu, const float* __restrict__ psig,
    const int* __restrict__ mask2, const float* __restrict__ ws2,
    const float* __restrict__ r2mu, const float* __restrict__ r2sg,
    float* __restrict__ out_mu, float* __restrict__ out_sig)
{
  const int row = blockIdx.x;
  const int tid = threadIdx.x;
  const float rterm = r2mu[row] + r2sg[row];
  const size_t sstride = (size_t)Mrows * N2;
  const float4* mup0 = (const float4*)(pmu + (size_t)row * N2);
  const float4* sbp0 = (const float4*)(psig + (size_t)row * N2);
  const int4* mkp = (const int4*)(mask2 + (size_t)row * N2);
  const float4* wsp = (const float4*)ws2;
  float4* omp = (float4*)(out_mu + (size_t)row * N2);
  float4* osp = (float4*)(out_sig + (size_t)row * N2);
  const size_t s4 = sstride / 4;
  for (int j = tid; j < N2 / 4; j += 256) {
    float4 m4 = mup0[j];
    float4 sb = sbp0[j];
#pragma unroll
    for (int s = 1; s < SPLITK; s++) {
      float4 a = mup0[j + s * s4];
      float4 b = sbp0[j + s * s4];
      m4.x += a.x; m4.y += a.y; m4.z += a.z; m4.w += a.w;
      sb.x += b.x; sb.y += b.y; sb.z += b.z; sb.w += b.w;
    }
    int4 k4 = mkp[j]; float4 w4 = wsp[j];
    float mo[4], so[4];
    float mv[4] = {m4.x, m4.y, m4.z, m4.w};
    float sv[4] = {sb.x, sb.y, sb.z, sb.w};
    float wv[4] = {w4.x, w4.y, w4.z, w4.w};
    int   kv[4] = {k4.x, k4.y, k4.z, k4.w};
#pragma unroll
    for (int t = 0; t < 4; t++) {
      float sig4 = cleanf(sv[t] + rterm * wv[t]);
      float mm = (float)kv[t];
      float mu5 = mv[t] * mm * (1.f / 0.9f);
      float sig5 = cleanf(sig4 * mm * (1.f / 1152.f));
      mo[t] = mu5;
      so[t] = cleanf(sig5);
    }
    omp[j] = make_float4(mo[0], mo[1], mo[2], mo[3]);
    osp[j] = make_float4(so[0], so[1], so[2], so[3]);
  }
}

// ---------------------------------------------------------------------------
extern "C" void kernel_launch(void* const* d_in, const int* in_sizes, int n_in,
                              void* d_out, int out_size, void* d_ws, size_t ws_size,
                              hipStream_t stream)
{
  const float* mu_in = (const float*)d_in[0];
  const float* sg_in = (const float*)d_in[1];
  const int* mask1 = (const int*)d_in[2];
  const int* mask2 = (const int*)d_in[3];
  const float* w_mu1 = (const float*)d_in[4];
  const float* wsig1 = (const float*)d_in[5];
  const float* w_mu2 = (const float*)d_in[6];
  const float* wsig2 = (const float*)d_in[7];
  float* out = (float*)d_out;

  char* ws = (char*)d_ws;
  // Fixed layout with explicit overlays (bytes):
  const size_t oA1  = 0;                           // 37,748,736  A1 / A2 (bf16)
  const size_t oAs  = oA1  + (size_t)37748736;     // As / As2 (fp8, uses half)
  const size_t oB1t = oAs  + (size_t)37748736;     // 42,467,328  B1t ; later pmu
  const size_t oB1q = oB1t + (size_t)42467328;     // B1q (fp8, uses half)
  const size_t oB2t = oB1q + (size_t)42467328;     // 10,616,832
  const size_t oB2q = oB2t + (size_t)10616832;     // B2q (fp8, uses half)
  const size_t oMu1 = oB2q + (size_t)10616832;     // 37,748,736  mu1b ; later psig
  const size_t oS1  = oMu1 + (size_t)37748736;     // S1b16
  const size_t oVec = oS1  + (size_t)37748736;

  unsigned short* A1    = (unsigned short*)(ws + oA1);
  unsigned char*  As8   = (unsigned char*)(ws + oAs);
  unsigned short* B1t   = (unsigned short*)(ws + oB1t);
  unsigned char*  B1q8  = (unsigned char*)(ws + oB1q);
  unsigned short* B2t   = (unsigned short*)(ws + oB2t);
  unsigned char*  B2q8  = (unsigned char*)(ws + oB2q);
  unsigned short* mu1b  = (unsigned short*)(ws + oMu1);
  unsigned short* S1b16 = (unsigned short*)(ws + oS1);
  float* pmu  = (float*)(ws + oB1t);   // SPLITK x M x N2 f32 partials
  float* psig = (float*)(ws + oMu1);   // SPLITK x M x N2 f32 partials

  float* rmu2 = (float*)(ws + oVec);
  float* rsg  = rmu2 + Mrows;
  float* r2mu = rsg + Mrows;
  float* r2sg = r2mu + Mrows;
  float* ws1v = r2sg + Mrows;
  float* ws2v = ws1v + N1;
  float* part1 = ws2v + N2;            // NPART1 floats
  float* part2 = part1 + NPART1;       // NPART2 floats

  prep_in<<<Mrows, 256, 0, stream>>>(mu_in, sg_in, A1, As8, rmu2, rsg);
  prep_w<<<dim3(K1 / 32, N1 / 32), 256, 0, stream>>>(w_mu1, B1t, B1q8, part1, K1, N1);
  prep_w<<<dim3(K1 / 32, N2 / 32), 256, 0, stream>>>(w_mu2, B2t, B2q8, part2, K1, N2);
  kl_prep<<<1, 256, 0, stream>>>(wsig1, wsig2, part1, part2, ws1v, ws2v,
                                 out + (size_t)2 * Mrows * N2);

  // layer 1: mu(bf16) + sigma(fp8) z-packed in one dispatch
  gemm_bt2<unsigned short><<<dim3(N1 / 128, Mrows / 128, 2), 256, 0, stream>>>(
      A1, As8, B1t, B1q8, mu1b, S1b16, Mrows, N1, K1, K1, DSC_L1);

  mid_kernel<<<Mrows, 256, 0, stream>>>(mu1b, S1b16, mask1, ws1v, rmu2, rsg,
                                        A1, As8, r2mu, r2sg);

  // layer 2: both products x split-K=2 z-packed
  gemm_bt2<float><<<dim3(N2 / 128, Mrows / 128, 2 * SPLITK), 256, 0, stream>>>(
      A1, As8, B2t, B2q8, pmu, psig, Mrows, N2, K1, K1 / SPLITK, DSC_L2);

  final_kernel<<<Mrows, 256, 0, stream>>>(pmu, psig, mask2, ws2v, r2mu, r2sg,
                                          out, out + (size_t)Mrows * N2);
  (void)in_sizes; (void)n_in; (void)out_size; (void)ws_size;
}